// Round 9
// baseline (742.569 us; speedup 1.0000x reference)
//
#include <hip/hip_runtime.h>
#include <math.h>

typedef __bf16 v8bf __attribute__((ext_vector_type(8)));
typedef float  v16f __attribute__((ext_vector_type(16)));

#define EPS_BN 1e-5f
#define Q_TOTAL 16384
#define N_MEM   262144
#define SLICES  16
#define SLICE_LEN (N_MEM / SLICES)   /* 16384 */
#define CHUNK   128
#define NCHUNKS (SLICE_LEN / CHUNK)  /* 128 */

// async global->LDS, 16B/lane. LDS dest is wave-uniform base + lane*16, so
// the bank swizzle must be folded into the GLOBAL source addresses.
__device__ __forceinline__ void gload_lds16(const void* g, void* l) {
    __builtin_amdgcn_global_load_lds(
        (const __attribute__((address_space(1))) void*)g,
        (__attribute__((address_space(3))) void*)l, 16, 0, 0);
}

// ---------------------------------------------------------------------------
// conv0: [256,1,64,64] -> [256,16,32,32], 3x3 s2 p1 + BN + ReLU
__global__ void conv0_kernel(const float* __restrict__ x,
                             const float* __restrict__ w, const float* __restrict__ bias,
                             const float* __restrict__ gamma, const float* __restrict__ beta,
                             const float* __restrict__ mean, const float* __restrict__ var,
                             float* __restrict__ out) {
    int idx = blockIdx.x * 256 + threadIdx.x;
    int xo = idx & 31, yo = (idx >> 5) & 31, c = (idx >> 10) & 15, b = idx >> 14;
    const float* xp = x + (size_t)b * 4096;
    const float* wc = w + c * 9;
    float acc = 0.f;
#pragma unroll
    for (int dy = 0; dy < 3; ++dy) {
        int iy = 2 * yo + dy - 1;
        if (iy < 0) continue;
#pragma unroll
        for (int dx = 0; dx < 3; ++dx) {
            int ix = 2 * xo + dx - 1;
            if (ix < 0) continue;
            acc += wc[dy * 3 + dx] * xp[iy * 64 + ix];
        }
    }
    acc += bias[c];
    float sc = gamma[c] * rsqrtf(var[c] + EPS_BN);
    float v  = (acc - mean[c]) * sc + beta[c];
    out[idx] = fmaxf(v, 0.f);
}

// ---------------------------------------------------------------------------
// conv1: [256,16,32,32] -> [256,32,16,16]. LDS-staged per (image, 8-ch group).
__global__ void conv1_kernel(const float* __restrict__ in,
                             const float* __restrict__ w, const float* __restrict__ bias,
                             const float* __restrict__ gamma, const float* __restrict__ beta,
                             const float* __restrict__ mean, const float* __restrict__ var,
                             float* __restrict__ out) {
    __shared__ float in_s[16384];
    __shared__ float w_s[1152];
    __shared__ float sc_s[8], sh_s[8];
    int b = blockIdx.x >> 2, cg = blockIdx.x & 3;
    int t = threadIdx.x;
    const float4* ip4 = (const float4*)(in + (size_t)b * 16384);
    float4* is4 = (float4*)in_s;
    for (int i = t; i < 4096; i += 256) is4[i] = ip4[i];
    for (int i = t; i < 1152; i += 256) w_s[i] = w[cg * 1152 + i];
    if (t < 8) {
        int c = cg * 8 + t;
        float sc = gamma[c] * rsqrtf(var[c] + EPS_BN);
        sc_s[t] = sc;
        sh_s[t] = (bias[c] - mean[c]) * sc + beta[c];
    }
    __syncthreads();
    int xo = t & 15, yo = t >> 4;
    float acc[8];
#pragma unroll
    for (int c = 0; c < 8; ++c) acc[c] = 0.f;
    int iy0 = 2 * yo - 1, ix0 = 2 * xo - 1;
    for (int ci = 0; ci < 16; ++ci) {
        const float* base = in_s + ci * 1024;
        float r[9];
#pragma unroll
        for (int dy = 0; dy < 3; ++dy) {
            int iy = iy0 + dy;
            int iyc = iy < 0 ? 0 : iy;
#pragma unroll
            for (int dx = 0; dx < 3; ++dx) {
                int ix = ix0 + dx;
                int ixc = ix < 0 ? 0 : ix;
                float v = base[iyc * 32 + ixc];
                r[dy * 3 + dx] = (iy >= 0 && ix >= 0) ? v : 0.f;
            }
        }
#pragma unroll
        for (int c = 0; c < 8; ++c) {
            const float* wp = w_s + (c * 16 + ci) * 9;
#pragma unroll
            for (int k = 0; k < 9; ++k) acc[c] = fmaf(wp[k], r[k], acc[c]);
        }
    }
#pragma unroll
    for (int c = 0; c < 8; ++c) {
        float v = fmaf(acc[c], sc_s[c], sh_s[c]);
        out[((size_t)(b * 32 + cg * 8 + c) * 16 + yo) * 16 + xo] = fmaxf(v, 0.f);
    }
}

// ---------------------------------------------------------------------------
// conv2: [256,32,16,16] -> [256,64,8,8]. LDS-staged per (image, 16-ch group).
__global__ void conv2_kernel(const float* __restrict__ in,
                             const float* __restrict__ w, const float* __restrict__ bias,
                             const float* __restrict__ gamma, const float* __restrict__ beta,
                             const float* __restrict__ mean, const float* __restrict__ var,
                             float* __restrict__ out) {
    __shared__ float in_s[8192];
    __shared__ float w_s[4608];
    __shared__ float sc_s[16], sh_s[16];
    int b = blockIdx.x >> 2, cg = blockIdx.x & 3;
    int t = threadIdx.x;
    const float4* ip4 = (const float4*)(in + (size_t)b * 8192);
    float4* is4 = (float4*)in_s;
    for (int i = t; i < 2048; i += 256) is4[i] = ip4[i];
    for (int i = t; i < 4608; i += 256) w_s[i] = w[cg * 4608 + i];
    if (t < 16) {
        int c = cg * 16 + t;
        float sc = gamma[c] * rsqrtf(var[c] + EPS_BN);
        sc_s[t] = sc;
        sh_s[t] = (bias[c] - mean[c]) * sc + beta[c];
    }
    __syncthreads();
    int xo = t & 7, yo = (t >> 3) & 7, cs = t >> 6;
    float acc[4];
#pragma unroll
    for (int l = 0; l < 4; ++l) acc[l] = 0.f;
    int iy0 = 2 * yo - 1, ix0 = 2 * xo - 1;
    for (int ci = 0; ci < 32; ++ci) {
        const float* base = in_s + ci * 256;
        float r[9];
#pragma unroll
        for (int dy = 0; dy < 3; ++dy) {
            int iy = iy0 + dy;
            int iyc = iy < 0 ? 0 : iy;
#pragma unroll
            for (int dx = 0; dx < 3; ++dx) {
                int ix = ix0 + dx;
                int ixc = ix < 0 ? 0 : ix;
                float v = base[iyc * 16 + ixc];
                r[dy * 3 + dx] = (iy >= 0 && ix >= 0) ? v : 0.f;
            }
        }
#pragma unroll
        for (int l = 0; l < 4; ++l) {
            const float* wp = w_s + ((cs * 4 + l) * 32 + ci) * 9;
#pragma unroll
            for (int k = 0; k < 9; ++k) acc[l] = fmaf(wp[k], r[k], acc[l]);
        }
    }
#pragma unroll
    for (int l = 0; l < 4; ++l) {
        int c = cg * 16 + cs * 4 + l;
        float v = fmaf(acc[l], sc_s[cs * 4 + l], sh_s[cs * 4 + l]);
        out[((size_t)(b * 64 + c) * 8 + yo) * 8 + xo] = fmaxf(v, 0.f);
    }
}

// ---------------------------------------------------------------------------
// qnorm: y2 [256,64,8,8] -> transpose -> L2 normalize -> bf16; qsq from the
// bf16-rounded values. Also initializes mind2 (+inf) for the dist kernel.
__global__ void qnorm_kernel(const float* __restrict__ y2,
                             __bf16* __restrict__ q, float* __restrict__ qsq,
                             unsigned int* __restrict__ mind2) {
    __shared__ float  L1s[4096];
    __shared__ __bf16 L2s[4096];
    int b = blockIdx.x, t = threadIdx.x;          // 64 threads
    mind2[b * 64 + t] = 0x7f800000u;              // +inf init
    const float* src = y2 + (size_t)b * 4096;
    for (int i = t; i < 4096; i += 64) L1s[i] = src[i];
    __syncthreads();
    int p = t;
    float ss = 0.f;
    for (int d = 0; d < 64; ++d) { float v = L1s[d * 64 + p]; ss += v * v; }
    float inv = 1.f / fmaxf(sqrtf(ss), 1e-12f);
    float q2 = 0.f;
    for (int d = 0; d < 64; ++d) {
        float v = L1s[d * 64 + p] * inv;
        __bf16 bv = (__bf16)v;
        L2s[p * 64 + d] = bv;
        float fb = (float)bv;
        q2 += fb * fb;
    }
    qsq[b * 64 + p] = q2;
    __syncthreads();
    for (int p2 = 0; p2 < 64; ++p2)
        q[((size_t)(b * 64 + p2)) * 64 + t] = L2s[p2 * 64 + t];
}

// mbnorm: normalize bank rows, pack bf16. msq := 1 in dist (unit rows).
__global__ void mbnorm_kernel(const float* __restrict__ mb,
                              __bf16* __restrict__ mbbf) {
    int row  = blockIdx.x * 4 + (threadIdx.x >> 6);
    int lane = threadIdx.x & 63;
    float v = mb[(size_t)row * 64 + lane];
    float ss = v * v;
#pragma unroll
    for (int o = 1; o < 64; o <<= 1) ss += __shfl_xor(ss, o, 64);
    float inv = 1.f / fmaxf(sqrtf(ss), 1e-12f);
    mbbf[(size_t)row * 64 + lane] = (__bf16)(v * inv);
}

// ---------------------------------------------------------------------------
// dist v9 = v8 with CHUNK halved to 128 (2x16 KB LDS): v8's occupancy was
// LDS-bound (64 KB -> 2 blocks/CU = 2 waves/SIMD) while VGPR=128 permits 4
// waves/SIMD. At 2 waves/SIMD the ~90% per-wave VALU:MFMA ratio couldn't
// overlap across waves (MfmaUtil stuck at 55%). 32 KB LDS -> 4 blocks/CU =
// 16 waves/CU (50%), doubling the MFMA/VALU wave-level overlap (m114).
// Grid 64x16 = 1024 = exactly 4 blocks/CU. Same copyless max3 pairing.
__global__ __launch_bounds__(256)
void dist_kernel(const __bf16* __restrict__ q, const float* __restrict__ qsq,
                 const __bf16* __restrict__ mb,
                 unsigned int* __restrict__ mind2) {
    __shared__ __align__(16) __bf16 Bs[2][CHUNK * 64];   // 2 x 16 KB
    const int t = threadIdx.x;
    const int wave = t >> 6, lane = t & 63;
    const int n32 = lane & 31, half = lane >> 5;
    const int mbase = blockIdx.x * 256 + wave * 64;
    const int slice = blockIdx.y;

    // A fragments: 2 strips x 4 ksteps (32 VGPR).
    v8bf a[2][4];
#pragma unroll
    for (int s = 0; s < 2; ++s)
#pragma unroll
        for (int ks = 0; ks < 4; ++ks)
            a[s][ks] = *(const v8bf*)(q + (size_t)(mbase + s * 32 + n32) * 64
                                        + ks * 16 + half * 8);

    float tmax[2][16];
#pragma unroll
    for (int s = 0; s < 2; ++s)
#pragma unroll
        for (int r = 0; r < 16; ++r) tmax[s][r] = -3.0e38f;

    v16f Z;                       // hoisted zero C-operand
#pragma unroll
    for (int r = 0; r < 16; ++r) Z[r] = 0.f;

    // staging: granule g=j*256+t -> row g>>3, pos (g&7)^(row&7); set j at
    // LDS offset j*4096 (j*32 ≡ 0 mod 8 -> swizzle j-invariant). 4 sets/chunk.
    const int r0 = t >> 3, c0 = (t & 7) ^ (r0 & 7);
    const __bf16* gp = mb + (size_t)slice * SLICE_LEN * 64 + r0 * 64 + c0 * 8;
    const int wbase = wave * 1024;

    // prologue: chunk 0 -> buf 0
#pragma unroll
    for (int j = 0; j < 4; ++j) {
        gload_lds16(gp, (char*)Bs[0] + j * 4096 + wbase);
        gp += 2048;
    }

    // ds_read offsets (tile-invariant: n&7 == n32&7); tile nt at +nt*4096
    const int sw = (n32 & 7) << 4;
    int offk[4];
#pragma unroll
    for (int ks = 0; ks < 4; ++ks) offk[ks] = (((ks * 2 + half) << 4) ^ sw);

    auto step = [&](const char* bp, char* pdst, bool more) {
        __syncthreads();          // drains staging (vmcnt0) + sync
        if (more) {
#pragma unroll
            for (int j = 0; j < 4; ++j) {
                gload_lds16(gp, pdst + j * 4096 + wbase);
                gp += 2048;
            }
        }
        const char* tp = bp + n32 * 128;
        v8bf be[4], bo[4];
#pragma unroll
        for (int ks = 0; ks < 4; ++ks) {
            be[ks] = *(const v8bf*)(tp + offk[ks]);           // tile 0
            bo[ks] = *(const v8bf*)(tp + 4096 + offk[ks]);    // tile 1
        }
#pragma unroll 1
        for (int p = 0; p < 2; ++p) {
            // even tile (be is dead after these issue)
            v16f A0 = __builtin_amdgcn_mfma_f32_32x32x16_bf16(a[0][0], be[0], Z, 0, 0, 0);
            v16f A1 = __builtin_amdgcn_mfma_f32_32x32x16_bf16(a[1][0], be[0], Z, 0, 0, 0);
#pragma unroll
            for (int ks = 1; ks < 4; ++ks) {
                A0 = __builtin_amdgcn_mfma_f32_32x32x16_bf16(a[0][ks], be[ks], A0, 0, 0, 0);
                A1 = __builtin_amdgcn_mfma_f32_32x32x16_bf16(a[1][ks], be[ks], A1, 0, 0, 0);
            }
            // odd tile
            v16f B0 = __builtin_amdgcn_mfma_f32_32x32x16_bf16(a[0][0], bo[0], Z, 0, 0, 0);
            v16f B1 = __builtin_amdgcn_mfma_f32_32x32x16_bf16(a[1][0], bo[0], Z, 0, 0, 0);
#pragma unroll
            for (int ks = 1; ks < 4; ++ks) {
                B0 = __builtin_amdgcn_mfma_f32_32x32x16_bf16(a[0][ks], bo[ks], B0, 0, 0, 0);
                B1 = __builtin_amdgcn_mfma_f32_32x32x16_bf16(a[1][ks], bo[ks], B1, 0, 0, 0);
            }
            // reload be/bo in place for the next pair (no copies)
            if (p < 1) {
                const char* tn = tp + 8192;
#pragma unroll
                for (int ks = 0; ks < 4; ++ks) {
                    be[ks] = *(const v8bf*)(tn + offk[ks]);
                    bo[ks] = *(const v8bf*)(tn + 4096 + offk[ks]);
                }
            }
            // fold both tiles: fmax(fmax(.,.),.) -> v_max3_f32
#pragma unroll
            for (int r = 0; r < 16; ++r) {
                tmax[0][r] = fmaxf(fmaxf(A0[r], B0[r]), tmax[0][r]);
                tmax[1][r] = fmaxf(fmaxf(A1[r], B1[r]), tmax[1][r]);
            }
        }
    };

    for (int ch = 0; ch < NCHUNKS; ch += 2) {
        step((const char*)Bs[0], (char*)Bs[1], ch + 1 < NCHUNKS);
        step((const char*)Bs[1], (char*)Bs[0], ch + 2 < NCHUNKS);
    }

    // cross-lane max over the 32 columns
#pragma unroll
    for (int s = 0; s < 2; ++s)
#pragma unroll
        for (int r = 0; r < 16; ++r) {
            float v = tmax[s][r];
            v = fmaxf(v, __shfl_xor(v, 1, 64));
            v = fmaxf(v, __shfl_xor(v, 2, 64));
            v = fmaxf(v, __shfl_xor(v, 4, 64));
            v = fmaxf(v, __shfl_xor(v, 8, 64));
            v = fmaxf(v, __shfl_xor(v, 16, 64));
            tmax[s][r] = v;
        }
    if (n32 == 0) {
#pragma unroll
        for (int s = 0; s < 2; ++s)
#pragma unroll
            for (int r = 0; r < 16; ++r) {
                int row = (r & 3) + 8 * (r >> 2) + 4 * half;  // C/D row map
                int m = mbase + s * 32 + row;
                // d^2 = qsq + |m|^2 - 2 dot, |m|^2 := 1 (unit rows)
                float dd = fmaxf(qsq[m] + 1.0f - 2.0f * tmax[s][r], 0.f);
                atomicMin(mind2 + m, __float_as_uint(dd));
            }
    }
}

// finalize: out[b] = max_p sqrt(mind2[b*64+p])
__global__ void finalize_kernel(const unsigned int* __restrict__ mind2,
                                float* __restrict__ out) {
    int b = blockIdx.x, l = threadIdx.x;
    float v = __uint_as_float(mind2[b * 64 + l]);
    float d = sqrtf(fmaxf(v, 0.f));
#pragma unroll
    for (int o = 1; o < 64; o <<= 1) d = fmaxf(d, __shfl_xor(d, o, 64));
    if (l == 0) out[b] = d;
}

// ---------------------------------------------------------------------------
extern "C" void kernel_launch(void* const* d_in, const int* in_sizes, int n_in,
                              void* d_out, int out_size, void* d_ws, size_t ws_size,
                              hipStream_t stream) {
    (void)in_sizes; (void)n_in; (void)out_size; (void)ws_size;
    const float* x     = (const float*)d_in[0];
    const float* mbank = (const float*)d_in[1];
    const float* w0 = (const float*)d_in[2],  *b0 = (const float*)d_in[3];
    const float* g0 = (const float*)d_in[4],  *be0 = (const float*)d_in[5];
    const float* mn0 = (const float*)d_in[6], *vr0 = (const float*)d_in[7];
    const float* w1 = (const float*)d_in[8],  *b1 = (const float*)d_in[9];
    const float* g1 = (const float*)d_in[10], *be1 = (const float*)d_in[11];
    const float* mn1 = (const float*)d_in[12], *vr1 = (const float*)d_in[13];
    const float* w2 = (const float*)d_in[14], *b2 = (const float*)d_in[15];
    const float* g2 = (const float*)d_in[16], *be2 = (const float*)d_in[17];
    const float* mn2 = (const float*)d_in[18], *vr2 = (const float*)d_in[19];

    char* ws = (char*)d_ws;
    float*        y0    = (float*)(ws + 0);              // 16.78 MB
    float*        y1    = (float*)(ws + 16777216);       // 8.39 MB
    float*        y2    = (float*)(ws + 25165824);       // 4.19 MB
    __bf16*       qbf   = (__bf16*)(ws + 29360128);      // 2.10 MB
    float*        qsq   = (float*)(ws + 31457280);       // 64 KB
    __bf16*       mbbf  = (__bf16*)(ws + 31522816);      // 33.55 MB
    unsigned int* mind2 = (unsigned int*)(ws + 66125824);// 64 KB

    conv0_kernel<<<16384, 256, 0, stream>>>(x, w0, b0, g0, be0, mn0, vr0, y0);
    conv1_kernel<<<1024, 256, 0, stream>>>(y0, w1, b1, g1, be1, mn1, vr1, y1);
    conv2_kernel<<<1024, 256, 0, stream>>>(y1, w2, b2, g2, be2, mn2, vr2, y2);
    qnorm_kernel<<<256, 64, 0, stream>>>(y2, qbf, qsq, mind2);
    mbnorm_kernel<<<65536, 256, 0, stream>>>(mbank, mbbf);
    dist_kernel<<<dim3(64, SLICES), 256, 0, stream>>>(qbf, qsq, mbbf, mind2);
    finalize_kernel<<<256, 64, 0, stream>>>(mind2, (float*)d_out);
}

// Round 10
// 699.366 us; speedup vs baseline: 1.0618x; 1.0618x over previous
//
#include <hip/hip_runtime.h>
#include <math.h>

typedef __bf16 v8bf __attribute__((ext_vector_type(8)));
typedef __bf16 v4bf __attribute__((ext_vector_type(4)));
typedef float  v16f __attribute__((ext_vector_type(16)));
typedef float  v4f  __attribute__((ext_vector_type(4)));

#define EPS_BN 1e-5f
#define Q_TOTAL 16384
#define N_MEM   262144
#define SLICES  16
#define SLICE_LEN (N_MEM / SLICES)   /* 16384 */
#define CHUNK   256
#define NCHUNKS (SLICE_LEN / CHUNK)  /* 64 */

// async global->LDS, 16B/lane. LDS dest is wave-uniform base + lane*16, so
// the bank swizzle must be folded into the GLOBAL source addresses.
__device__ __forceinline__ void gload_lds16(const void* g, void* l) {
    __builtin_amdgcn_global_load_lds(
        (const __attribute__((address_space(1))) void*)g,
        (__attribute__((address_space(3))) void*)l, 16, 0, 0);
}

// ---------------------------------------------------------------------------
// conv0: [256,1,64,64] -> [256,16,32,32], 3x3 s2 p1 + BN + ReLU
__global__ void conv0_kernel(const float* __restrict__ x,
                             const float* __restrict__ w, const float* __restrict__ bias,
                             const float* __restrict__ gamma, const float* __restrict__ beta,
                             const float* __restrict__ mean, const float* __restrict__ var,
                             float* __restrict__ out) {
    int idx = blockIdx.x * 256 + threadIdx.x;
    int xo = idx & 31, yo = (idx >> 5) & 31, c = (idx >> 10) & 15, b = idx >> 14;
    const float* xp = x + (size_t)b * 4096;
    const float* wc = w + c * 9;
    float acc = 0.f;
#pragma unroll
    for (int dy = 0; dy < 3; ++dy) {
        int iy = 2 * yo + dy - 1;
        if (iy < 0) continue;
#pragma unroll
        for (int dx = 0; dx < 3; ++dx) {
            int ix = 2 * xo + dx - 1;
            if (ix < 0) continue;
            acc += wc[dy * 3 + dx] * xp[iy * 64 + ix];
        }
    }
    acc += bias[c];
    float sc = gamma[c] * rsqrtf(var[c] + EPS_BN);
    float v  = (acc - mean[c]) * sc + beta[c];
    out[idx] = fmaxf(v, 0.f);
}

// ---------------------------------------------------------------------------
// conv1: [256,16,32,32] -> [256,32,16,16]. LDS-staged per (image, 8-ch group).
__global__ void conv1_kernel(const float* __restrict__ in,
                             const float* __restrict__ w, const float* __restrict__ bias,
                             const float* __restrict__ gamma, const float* __restrict__ beta,
                             const float* __restrict__ mean, const float* __restrict__ var,
                             float* __restrict__ out) {
    __shared__ float in_s[16384];
    __shared__ float w_s[1152];
    __shared__ float sc_s[8], sh_s[8];
    int b = blockIdx.x >> 2, cg = blockIdx.x & 3;
    int t = threadIdx.x;
    const float4* ip4 = (const float4*)(in + (size_t)b * 16384);
    float4* is4 = (float4*)in_s;
    for (int i = t; i < 4096; i += 256) is4[i] = ip4[i];
    for (int i = t; i < 1152; i += 256) w_s[i] = w[cg * 1152 + i];
    if (t < 8) {
        int c = cg * 8 + t;
        float sc = gamma[c] * rsqrtf(var[c] + EPS_BN);
        sc_s[t] = sc;
        sh_s[t] = (bias[c] - mean[c]) * sc + beta[c];
    }
    __syncthreads();
    int xo = t & 15, yo = t >> 4;
    float acc[8];
#pragma unroll
    for (int c = 0; c < 8; ++c) acc[c] = 0.f;
    int iy0 = 2 * yo - 1, ix0 = 2 * xo - 1;
    for (int ci = 0; ci < 16; ++ci) {
        const float* base = in_s + ci * 1024;
        float r[9];
#pragma unroll
        for (int dy = 0; dy < 3; ++dy) {
            int iy = iy0 + dy;
            int iyc = iy < 0 ? 0 : iy;
#pragma unroll
            for (int dx = 0; dx < 3; ++dx) {
                int ix = ix0 + dx;
                int ixc = ix < 0 ? 0 : ix;
                float v = base[iyc * 32 + ixc];
                r[dy * 3 + dx] = (iy >= 0 && ix >= 0) ? v : 0.f;
            }
        }
#pragma unroll
        for (int c = 0; c < 8; ++c) {
            const float* wp = w_s + (c * 16 + ci) * 9;
#pragma unroll
            for (int k = 0; k < 9; ++k) acc[c] = fmaf(wp[k], r[k], acc[c]);
        }
    }
#pragma unroll
    for (int c = 0; c < 8; ++c) {
        float v = fmaf(acc[c], sc_s[c], sh_s[c]);
        out[((size_t)(b * 32 + cg * 8 + c) * 16 + yo) * 16 + xo] = fmaxf(v, 0.f);
    }
}

// ---------------------------------------------------------------------------
// conv2: [256,32,16,16] -> [256,64,8,8]. LDS-staged per (image, 16-ch group).
__global__ void conv2_kernel(const float* __restrict__ in,
                             const float* __restrict__ w, const float* __restrict__ bias,
                             const float* __restrict__ gamma, const float* __restrict__ beta,
                             const float* __restrict__ mean, const float* __restrict__ var,
                             float* __restrict__ out) {
    __shared__ float in_s[8192];
    __shared__ float w_s[4608];
    __shared__ float sc_s[16], sh_s[16];
    int b = blockIdx.x >> 2, cg = blockIdx.x & 3;
    int t = threadIdx.x;
    const float4* ip4 = (const float4*)(in + (size_t)b * 8192);
    float4* is4 = (float4*)in_s;
    for (int i = t; i < 2048; i += 256) is4[i] = ip4[i];
    for (int i = t; i < 4608; i += 256) w_s[i] = w[cg * 4608 + i];
    if (t < 16) {
        int c = cg * 16 + t;
        float sc = gamma[c] * rsqrtf(var[c] + EPS_BN);
        sc_s[t] = sc;
        sh_s[t] = (bias[c] - mean[c]) * sc + beta[c];
    }
    __syncthreads();
    int xo = t & 7, yo = (t >> 3) & 7, cs = t >> 6;
    float acc[4];
#pragma unroll
    for (int l = 0; l < 4; ++l) acc[l] = 0.f;
    int iy0 = 2 * yo - 1, ix0 = 2 * xo - 1;
    for (int ci = 0; ci < 32; ++ci) {
        const float* base = in_s + ci * 256;
        float r[9];
#pragma unroll
        for (int dy = 0; dy < 3; ++dy) {
            int iy = iy0 + dy;
            int iyc = iy < 0 ? 0 : iy;
#pragma unroll
            for (int dx = 0; dx < 3; ++dx) {
                int ix = ix0 + dx;
                int ixc = ix < 0 ? 0 : ix;
                float v = base[iyc * 16 + ixc];
                r[dy * 3 + dx] = (iy >= 0 && ix >= 0) ? v : 0.f;
            }
        }
#pragma unroll
        for (int l = 0; l < 4; ++l) {
            const float* wp = w_s + ((cs * 4 + l) * 32 + ci) * 9;
#pragma unroll
            for (int k = 0; k < 9; ++k) acc[l] = fmaf(wp[k], r[k], acc[l]);
        }
    }
#pragma unroll
    for (int l = 0; l < 4; ++l) {
        int c = cg * 16 + cs * 4 + l;
        float v = fmaf(acc[l], sc_s[cs * 4 + l], sh_s[cs * 4 + l]);
        out[((size_t)(b * 64 + c) * 8 + yo) * 8 + xo] = fmaxf(v, 0.f);
    }
}

// ---------------------------------------------------------------------------
// qnorm: y2 [256,64,8,8] -> transpose -> L2 normalize -> bf16; qsq from the
// bf16-rounded values. Also initializes mind2 (+inf) for the dist kernel.
__global__ void qnorm_kernel(const float* __restrict__ y2,
                             __bf16* __restrict__ q, float* __restrict__ qsq,
                             unsigned int* __restrict__ mind2) {
    __shared__ float  L1s[4096];
    __shared__ __bf16 L2s[4096];
    int b = blockIdx.x, t = threadIdx.x;          // 64 threads
    mind2[b * 64 + t] = 0x7f800000u;              // +inf init
    const float* src = y2 + (size_t)b * 4096;
    for (int i = t; i < 4096; i += 64) L1s[i] = src[i];
    __syncthreads();
    int p = t;
    float ss = 0.f;
    for (int d = 0; d < 64; ++d) { float v = L1s[d * 64 + p]; ss += v * v; }
    float inv = 1.f / fmaxf(sqrtf(ss), 1e-12f);
    float q2 = 0.f;
    for (int d = 0; d < 64; ++d) {
        float v = L1s[d * 64 + p] * inv;
        __bf16 bv = (__bf16)v;
        L2s[p * 64 + d] = bv;
        float fb = (float)bv;
        q2 += fb * fb;
    }
    qsq[b * 64 + p] = q2;
    __syncthreads();
    for (int p2 = 0; p2 < 64; ++p2)
        q[((size_t)(b * 64 + p2)) * 64 + t] = L2s[p2 * 64 + t];
}

// ---------------------------------------------------------------------------
// mbnorm v2: 16 threads/row, float4 per thread (was 64 thr/row scalar + full
// 64-lane shuffle chain -> ~65k waves ~ 100+ us). Now 4.2M threads / 16k
// blocks, 4-step 16-lane reduction, vectorized 8B bf16 store. msq := 1 in
// dist (unit rows), so only the normalized bf16 row is produced.
__global__ void mbnorm_kernel(const float* __restrict__ mb,
                              __bf16* __restrict__ mbbf) {
    int tid = blockIdx.x * 256 + threadIdx.x;
    int row = tid >> 4, sub = tid & 15;
    const float4 v = *(const float4*)(mb + (size_t)row * 64 + sub * 4);
    float ss = v.x * v.x + v.y * v.y + v.z * v.z + v.w * v.w;
#pragma unroll
    for (int o = 1; o < 16; o <<= 1) ss += __shfl_xor(ss, o, 64);
    float inv = 1.f / fmaxf(sqrtf(ss), 1e-12f);
    v4bf o;
    o[0] = (__bf16)(v.x * inv);
    o[1] = (__bf16)(v.y * inv);
    o[2] = (__bf16)(v.z * inv);
    o[3] = (__bf16)(v.w * inv);
    *(v4bf*)(mbbf + (size_t)row * 64 + sub * 4) = o;
}

// ---------------------------------------------------------------------------
// dist v10 = v8 verbatim (best measured: 486 us). Plateau analysis: per CU
// MFMA 524k cyc, LDS 524k (ds_read_b128 ~16cyc incl 4-way structural alias),
// VALU ~450k — three co-binding pipes at 2 waves/SIMD (unified regs ~190:
// VGPR_Count 128 shows arch only; AGPR acc sets add ~64). CHUNK=256 beats
// 128 (fewer barriers, same occupancy — v9 measured).
__global__ __launch_bounds__(256)
void dist_kernel(const __bf16* __restrict__ q, const float* __restrict__ qsq,
                 const __bf16* __restrict__ mb,
                 unsigned int* __restrict__ mind2) {
    __shared__ __align__(16) __bf16 Bs[2][CHUNK * 64];   // 2 x 32 KB
    const int t = threadIdx.x;
    const int wave = t >> 6, lane = t & 63;
    const int n32 = lane & 31, half = lane >> 5;
    const int mbase = blockIdx.x * 256 + wave * 64;
    const int slice = blockIdx.y;

    // A fragments: 2 strips x 4 ksteps (32 VGPR).
    v8bf a[2][4];
#pragma unroll
    for (int s = 0; s < 2; ++s)
#pragma unroll
        for (int ks = 0; ks < 4; ++ks)
            a[s][ks] = *(const v8bf*)(q + (size_t)(mbase + s * 32 + n32) * 64
                                        + ks * 16 + half * 8);

    float tmax[2][16];
#pragma unroll
    for (int s = 0; s < 2; ++s)
#pragma unroll
        for (int r = 0; r < 16; ++r) tmax[s][r] = -3.0e38f;

    v16f Z;                       // hoisted zero C-operand
#pragma unroll
    for (int r = 0; r < 16; ++r) Z[r] = 0.f;

    // staging: granule g=j*256+t -> row g>>3, pos (g&7)^(row&7); set j at
    // LDS offset j*4096 (j*32 ≡ 0 mod 8 -> swizzle j-invariant).
    const int r0 = t >> 3, c0 = (t & 7) ^ (r0 & 7);
    const __bf16* gp = mb + (size_t)slice * SLICE_LEN * 64 + r0 * 64 + c0 * 8;
    const int wbase = wave * 1024;

    // prologue: chunk 0 -> buf 0
#pragma unroll
    for (int j = 0; j < 8; ++j) {
        gload_lds16(gp, (char*)Bs[0] + j * 4096 + wbase);
        gp += 2048;
    }

    // ds_read offsets (tile-invariant: n&7 == n32&7); tile nt at +nt*4096
    const int sw = (n32 & 7) << 4;
    int offk[4];
#pragma unroll
    for (int ks = 0; ks < 4; ++ks) offk[ks] = (((ks * 2 + half) << 4) ^ sw);

    auto step = [&](const char* bp, char* pdst, bool more) {
        __syncthreads();          // drains staging (vmcnt0) + sync
        if (more) {
#pragma unroll
            for (int j = 0; j < 8; ++j) {
                gload_lds16(gp, pdst + j * 4096 + wbase);
                gp += 2048;
            }
        }
        const char* tp = bp + n32 * 128;
        v8bf be[4], bo[4];
#pragma unroll
        for (int ks = 0; ks < 4; ++ks) {
            be[ks] = *(const v8bf*)(tp + offk[ks]);           // tile 0
            bo[ks] = *(const v8bf*)(tp + 4096 + offk[ks]);    // tile 1
        }
#pragma unroll 1
        for (int p = 0; p < 4; ++p) {
            // even tile (be is dead after these issue)
            v16f A0 = __builtin_amdgcn_mfma_f32_32x32x16_bf16(a[0][0], be[0], Z, 0, 0, 0);
            v16f A1 = __builtin_amdgcn_mfma_f32_32x32x16_bf16(a[1][0], be[0], Z, 0, 0, 0);
#pragma unroll
            for (int ks = 1; ks < 4; ++ks) {
                A0 = __builtin_amdgcn_mfma_f32_32x32x16_bf16(a[0][ks], be[ks], A0, 0, 0, 0);
                A1 = __builtin_amdgcn_mfma_f32_32x32x16_bf16(a[1][ks], be[ks], A1, 0, 0, 0);
            }
            // odd tile
            v16f B0 = __builtin_amdgcn_mfma_f32_32x32x16_bf16(a[0][0], bo[0], Z, 0, 0, 0);
            v16f B1 = __builtin_amdgcn_mfma_f32_32x32x16_bf16(a[1][0], bo[0], Z, 0, 0, 0);
#pragma unroll
            for (int ks = 1; ks < 4; ++ks) {
                B0 = __builtin_amdgcn_mfma_f32_32x32x16_bf16(a[0][ks], bo[ks], B0, 0, 0, 0);
                B1 = __builtin_amdgcn_mfma_f32_32x32x16_bf16(a[1][ks], bo[ks], B1, 0, 0, 0);
            }
            // reload be/bo in place for the next pair (no copies)
            if (p < 3) {
                const char* tn = tp + (p + 1) * 8192;
#pragma unroll
                for (int ks = 0; ks < 4; ++ks) {
                    be[ks] = *(const v8bf*)(tn + offk[ks]);
                    bo[ks] = *(const v8bf*)(tn + 4096 + offk[ks]);
                }
            }
            // fold both tiles: fmax(fmax(.,.),.) -> v_max3_f32
#pragma unroll
            for (int r = 0; r < 16; ++r) {
                tmax[0][r] = fmaxf(fmaxf(A0[r], B0[r]), tmax[0][r]);
                tmax[1][r] = fmaxf(fmaxf(A1[r], B1[r]), tmax[1][r]);
            }
        }
    };

    for (int ch = 0; ch < NCHUNKS; ch += 2) {
        step((const char*)Bs[0], (char*)Bs[1], ch + 1 < NCHUNKS);
        step((const char*)Bs[1], (char*)Bs[0], ch + 2 < NCHUNKS);
    }

    // cross-lane max over the 32 columns
#pragma unroll
    for (int s = 0; s < 2; ++s)
#pragma unroll
        for (int r = 0; r < 16; ++r) {
            float v = tmax[s][r];
            v = fmaxf(v, __shfl_xor(v, 1, 64));
            v = fmaxf(v, __shfl_xor(v, 2, 64));
            v = fmaxf(v, __shfl_xor(v, 4, 64));
            v = fmaxf(v, __shfl_xor(v, 8, 64));
            v = fmaxf(v, __shfl_xor(v, 16, 64));
            tmax[s][r] = v;
        }
    if (n32 == 0) {
#pragma unroll
        for (int s = 0; s < 2; ++s)
#pragma unroll
            for (int r = 0; r < 16; ++r) {
                int row = (r & 3) + 8 * (r >> 2) + 4 * half;  // C/D row map
                int m = mbase + s * 32 + row;
                // d^2 = qsq + |m|^2 - 2 dot, |m|^2 := 1 (unit rows)
                float dd = fmaxf(qsq[m] + 1.0f - 2.0f * tmax[s][r], 0.f);
                atomicMin(mind2 + m, __float_as_uint(dd));
            }
    }
}

// finalize: out[b] = max_p sqrt(mind2[b*64+p])
__global__ void finalize_kernel(const unsigned int* __restrict__ mind2,
                                float* __restrict__ out) {
    int b = blockIdx.x, l = threadIdx.x;
    float v = __uint_as_float(mind2[b * 64 + l]);
    float d = sqrtf(fmaxf(v, 0.f));
#pragma unroll
    for (int o = 1; o < 64; o <<= 1) d = fmaxf(d, __shfl_xor(d, o, 64));
    if (l == 0) out[b] = d;
}

// ---------------------------------------------------------------------------
extern "C" void kernel_launch(void* const* d_in, const int* in_sizes, int n_in,
                              void* d_out, int out_size, void* d_ws, size_t ws_size,
                              hipStream_t stream) {
    (void)in_sizes; (void)n_in; (void)out_size; (void)ws_size;
    const float* x     = (const float*)d_in[0];
    const float* mbank = (const float*)d_in[1];
    const float* w0 = (const float*)d_in[2],  *b0 = (const float*)d_in[3];
    const float* g0 = (const float*)d_in[4],  *be0 = (const float*)d_in[5];
    const float* mn0 = (const float*)d_in[6], *vr0 = (const float*)d_in[7];
    const float* w1 = (const float*)d_in[8],  *b1 = (const float*)d_in[9];
    const float* g1 = (const float*)d_in[10], *be1 = (const float*)d_in[11];
    const float* mn1 = (const float*)d_in[12], *vr1 = (const float*)d_in[13];
    const float* w2 = (const float*)d_in[14], *b2 = (const float*)d_in[15];
    const float* g2 = (const float*)d_in[16], *be2 = (const float*)d_in[17];
    const float* mn2 = (const float*)d_in[18], *vr2 = (const float*)d_in[19];

    char* ws = (char*)d_ws;
    float*        y0    = (float*)(ws + 0);              // 16.78 MB
    float*        y1    = (float*)(ws + 16777216);       // 8.39 MB
    float*        y2    = (float*)(ws + 25165824);       // 4.19 MB
    __bf16*       qbf   = (__bf16*)(ws + 29360128);      // 2.10 MB
    float*        qsq   = (float*)(ws + 31457280);       // 64 KB
    __bf16*       mbbf  = (__bf16*)(ws + 31522816);      // 33.55 MB
    unsigned int* mind2 = (unsigned int*)(ws + 66125824);// 64 KB

    conv0_kernel<<<16384, 256, 0, stream>>>(x, w0, b0, g0, be0, mn0, vr0, y0);
    conv1_kernel<<<1024, 256, 0, stream>>>(y0, w1, b1, g1, be1, mn1, vr1, y1);
    conv2_kernel<<<1024, 256, 0, stream>>>(y1, w2, b2, g2, be2, mn2, vr2, y2);
    qnorm_kernel<<<256, 64, 0, stream>>>(y2, qbf, qsq, mind2);
    mbnorm_kernel<<<16384, 256, 0, stream>>>(mbank, mbbf);
    dist_kernel<<<dim3(64, SLICES), 256, 0, stream>>>(qbf, qsq, mbbf, mind2);
    finalize_kernel<<<256, 64, 0, stream>>>(mind2, (float*)d_out);
}